// Round 6
// baseline (505.236 us; speedup 1.0000x reference)
//
#include <hip/hip_runtime.h>
#include <hip/hip_bf16.h>
#include <stdint.h>

#define BB 8
#define LL 4096
#define DD 64
#define KT2 128              // k-columns per iteration
#define NT2 (LL / KT2)       // 32 iterations

typedef short bf16x8 __attribute__((ext_vector_type(8)));
typedef short bf16x4 __attribute__((ext_vector_type(4)));
typedef float f32x4 __attribute__((ext_vector_type(4)));

__device__ inline short f2bfs(float x) {
    __hip_bfloat16 h = __float2bfloat16(x);
    return __builtin_bit_cast(short, h);
}

__device__ inline bf16x8 pack8v(f32x4 a, f32x4 b) {
    bf16x8 r;
    r[0] = f2bfs(a[0]); r[1] = f2bfs(a[1]); r[2] = f2bfs(a[2]); r[3] = f2bfs(a[3]);
    r[4] = f2bfs(b[0]); r[5] = f2bfs(b[1]); r[6] = f2bfs(b[2]); r[7] = f2bfs(b[3]);
    return r;
}

__device__ inline int swzf(int row) { return (row & 7) ^ ((row >> 3) & 7); }

__global__ void detect_mask_kernel(const uint32_t* __restrict__ w, uint32_t* __restrict__ flag) {
    __shared__ int nonbin;
    if (threadIdx.x == 0) nonbin = 0;
    __syncthreads();
    int bad = 0;
    for (int i = threadIdx.x; i < 4096; i += 256) bad |= (w[i] > 1u) ? 1 : 0;
    if (bad) atomicOr(&nonbin, 1);
    __syncthreads();
    if (threadIdx.x == 0) *flag = (uint32_t)(nonbin != 0);
}

// One block = 64 q-rows of one batch, 4 waves. Swapped QK^T (mfma(K,Q)) puts
// 4 consecutive k per lane -> vectorized mask loads (u32), attn stores (float4),
// Ps writes (b64). Pass 1: row sums (1 barrier/128k). Pass 2: recompute, write
// normalized attn, PV via swizzled Ps/Vt (2 barriers/128k). Mask re-read in
// pass 2 hits L3 (byte mask = 134 MB < 256 MB).
__global__ __launch_bounds__(256, 2) void fused_attn_kernel(
    const float* __restrict__ qg, const float* __restrict__ kg,
    const float* __restrict__ vg, const void* __restrict__ maskv,
    const uint32_t* __restrict__ flagp,
    float* __restrict__ attn, float* __restrict__ outp)
{
    __shared__ alignas(16) ushort Kt[2][KT2 * 64];   // bf16 K   [krow][d], swizzled 16B chunks
    __shared__ alignas(16) ushort Vt[2][64 * KT2];   // bf16 V^T [d][k],   swizzled
    __shared__ alignas(16) ushort Ps[64 * KT2];      // bf16 P   [q][k],   swizzled

    const int tid = (int)threadIdx.x;
    const int w   = tid >> 6;
    const int l   = tid & 63;
    const int lr  = l & 15, lg = l >> 4;
    const int id  = (int)blockIdx.x;     // id = qt*8 + b
    const int b   = id & 7;
    const int q0  = (id >> 3) * 64;
    const bool mbyte = (*flagp != 0);

    const float* kb = kg + (size_t)b * LL * DD;
    const float* vb = vg + (size_t)b * LL * DD;

    // this lane's q-row (scores): q = q0 + 16w + lr
    const int qrow = q0 + 16 * w + lr;
    const uint8_t* mrow8  = (const uint8_t*)maskv + (size_t)b * LL * LL + (size_t)qrow * LL;
    const int*     mrow32 = (const int*)maskv     + (size_t)b * LL * LL + (size_t)qrow * LL;
    float* arow = attn + (size_t)b * LL * LL + (size_t)qrow * LL;

    // Q fragments, pre-scaled by 1/8 (exact power-of-2; folds the SCALE away)
    bf16x8 qf[2];
    {
        const float* qp2 = qg + (size_t)(b * LL + qrow) * DD + lg * 8;
        f32x4 b0 = *(const f32x4*)(qp2)      * 0.125f;
        f32x4 b1 = *(const f32x4*)(qp2 + 4)  * 0.125f;
        f32x4 b2 = *(const f32x4*)(qp2 + 32) * 0.125f;
        f32x4 b3 = *(const f32x4*)(qp2 + 36) * 0.125f;
        qf[0] = pack8v(b0, b1);
        qf[1] = pack8v(b2, b3);
    }

    // ---- K staging: 128x64 f32 -> bf16, 8 float4 loads, 4 b128 commits ----
    const int krow0 = tid >> 3, kc8 = tid & 7;
    f32x4 ka[8];
    auto kissue = [&](int kbase) {
        #pragma unroll
        for (int m = 0; m < 4; ++m) {
            const float* p = kb + (size_t)(kbase + krow0 + 32 * m) * DD + kc8 * 8;
            ka[2 * m]     = *(const f32x4*)p;
            ka[2 * m + 1] = *(const f32x4*)(p + 4);
        }
    };
    auto kcommit = [&](int buf) {
        #pragma unroll
        for (int m = 0; m < 4; ++m) {
            const int row = krow0 + 32 * m;
            *(bf16x8*)&Kt[buf][row * 64 + ((kc8 ^ swzf(row)) << 3)] = pack8v(ka[2 * m], ka[2 * m + 1]);
        }
    };

    // ---- V staging: 4x4 sub-blocks, register transpose, 8 b64 commits ----
    const int vk4 = tid >> 4, vd4 = tid & 15;
    f32x4 va[8];   // [h*4 + it]: V[kbase + h*64 + vk4*4 + it][vd4*4 .. +3]
    auto vissue = [&](int kbase) {
        #pragma unroll
        for (int h = 0; h < 2; ++h)
            #pragma unroll
            for (int it = 0; it < 4; ++it)
                va[h * 4 + it] = *(const f32x4*)(vb + (size_t)(kbase + h * 64 + vk4 * 4 + it) * DD + vd4 * 4);
    };
    auto vcommit = [&](int buf) {
        #pragma unroll
        for (int h = 0; h < 2; ++h)
            #pragma unroll
            for (int e = 0; e < 4; ++e) {
                const int d = vd4 * 4 + e;
                bf16x4 t;
                t[0] = f2bfs(va[h * 4 + 0][e]);
                t[1] = f2bfs(va[h * 4 + 1][e]);
                t[2] = f2bfs(va[h * 4 + 2][e]);
                t[3] = f2bfs(va[h * 4 + 3][e]);
                const int chunk = h * 8 + (vk4 >> 1);
                const int swc = chunk ^ swzf(d);
                *(bf16x4*)&Vt[buf][d * KT2 + swc * 8 + (vk4 & 1) * 4] = t;
            }
    };

    // ================= pass 1: exp row sums =================
    float rsum = 0.f;
    kissue(0);
    kcommit(0);
    __syncthreads();
    #pragma unroll 1
    for (int kt = 0; kt < NT2; ++kt) {
        const int cur = kt & 1, kbase = kt * KT2;
        if (kt < NT2 - 1) kissue(kbase + KT2);
        #pragma unroll
        for (int n = 0; n < 8; ++n) {
            const int krow = n * 16 + lr;
            bf16x8 k0 = *(const bf16x8*)&Kt[cur][krow * 64 + ((lg       ^ swzf(krow)) << 3)];
            bf16x8 k1 = *(const bf16x8*)&Kt[cur][krow * 64 + (((4 + lg) ^ swzf(krow)) << 3)];
            f32x4 c = {0.f, 0.f, 0.f, 0.f};
            c = __builtin_amdgcn_mfma_f32_16x16x32_bf16(k0, qf[0], c, 0, 0, 0);
            c = __builtin_amdgcn_mfma_f32_16x16x32_bf16(k1, qf[1], c, 0, 0, 0);
            const int koff = kbase + n * 16 + lg * 4;
            if (mbyte) {
                const uint32_t mw = *(const uint32_t*)(mrow8 + koff);
                #pragma unroll
                for (int j = 0; j < 4; ++j)
                    rsum += ((mw >> (8 * j)) & 0xffu) ? 0.f : __expf(c[j]);
            } else {
                const int4 mi = *(const int4*)(mrow32 + koff);
                rsum += mi.x ? 0.f : __expf(c[0]);
                rsum += mi.y ? 0.f : __expf(c[1]);
                rsum += mi.z ? 0.f : __expf(c[2]);
                rsum += mi.w ? 0.f : __expf(c[3]);
            }
        }
        if (kt < NT2 - 1) kcommit((kt + 1) & 1);
        __syncthreads();
    }
    rsum += __shfl_xor(rsum, 16, 64);
    rsum += __shfl_xor(rsum, 32, 64);
    const float rinv = 1.0f / rsum;

    // ================= pass 2: attn write + PV =================
    f32x4 oacc[4];
    #pragma unroll
    for (int mt = 0; mt < 4; ++mt) { f32x4 z = {0.f, 0.f, 0.f, 0.f}; oacc[mt] = z; }

    kissue(0);
    vissue(0);
    kcommit(0);
    vcommit(0);
    __syncthreads();
    #pragma unroll 1
    for (int kt = 0; kt < NT2; ++kt) {
        const int cur = kt & 1, kbase = kt * KT2;
        if (kt < NT2 - 1) { kissue(kbase + KT2); vissue(kbase + KT2); }

        const int prow = 16 * w + lr;
        #pragma unroll
        for (int n = 0; n < 8; ++n) {
            const int krow = n * 16 + lr;
            bf16x8 k0 = *(const bf16x8*)&Kt[cur][krow * 64 + ((lg       ^ swzf(krow)) << 3)];
            bf16x8 k1 = *(const bf16x8*)&Kt[cur][krow * 64 + (((4 + lg) ^ swzf(krow)) << 3)];
            f32x4 c = {0.f, 0.f, 0.f, 0.f};
            c = __builtin_amdgcn_mfma_f32_16x16x32_bf16(k0, qf[0], c, 0, 0, 0);
            c = __builtin_amdgcn_mfma_f32_16x16x32_bf16(k1, qf[1], c, 0, 0, 0);
            const int koff = kbase + n * 16 + lg * 4;
            f32x4 pv;
            if (mbyte) {
                const uint32_t mw = *(const uint32_t*)(mrow8 + koff);
                #pragma unroll
                for (int j = 0; j < 4; ++j)
                    pv[j] = ((mw >> (8 * j)) & 0xffu) ? 0.f : __expf(c[j]) * rinv;
            } else {
                const int4 mi = *(const int4*)(mrow32 + koff);
                pv[0] = mi.x ? 0.f : __expf(c[0]) * rinv;
                pv[1] = mi.y ? 0.f : __expf(c[1]) * rinv;
                pv[2] = mi.z ? 0.f : __expf(c[2]) * rinv;
                pv[3] = mi.w ? 0.f : __expf(c[3]) * rinv;
            }
            *(f32x4*)(arow + koff) = pv;
            // Ps write: 4 consecutive k packed as b64
            bf16x4 pb;
            pb[0] = f2bfs(pv[0]); pb[1] = f2bfs(pv[1]);
            pb[2] = f2bfs(pv[2]); pb[3] = f2bfs(pv[3]);
            const int chunk = 2 * n + (lg >> 1);
            const int swc = chunk ^ swzf(prow);
            *(bf16x4*)&Ps[prow * KT2 + swc * 8 + (lg & 1) * 4] = pb;
        }
        __syncthreads();   // A: Ps complete; Vt[cur] staged last iteration

        {
            const int vrow = 16 * w + lr;    // this wave's d-column
            bf16x8 vf[4];
            #pragma unroll
            for (int kk = 0; kk < 4; ++kk)
                vf[kk] = *(const bf16x8*)&Vt[cur][vrow * KT2 + (((kk * 4 + lg) ^ swzf(vrow)) << 3)];
            #pragma unroll
            for (int mt = 0; mt < 4; ++mt) {
                const int pr = mt * 16 + lr;
                #pragma unroll
                for (int kk = 0; kk < 4; ++kk) {
                    bf16x8 pa = *(const bf16x8*)&Ps[pr * KT2 + (((kk * 4 + lg) ^ swzf(pr)) << 3)];
                    oacc[mt] = __builtin_amdgcn_mfma_f32_16x16x32_bf16(pa, vf[kk], oacc[mt], 0, 0, 0);
                }
            }
        }

        if (kt < NT2 - 1) { kcommit((kt + 1) & 1); vcommit((kt + 1) & 1); }
        __syncthreads();   // B: commits visible; Ps free for next iteration
    }

    #pragma unroll
    for (int mt = 0; mt < 4; ++mt)
        #pragma unroll
        for (int r = 0; r < 4; ++r)
            outp[(size_t)(b * LL + q0 + mt * 16 + lg * 4 + r) * DD + 16 * w + lr] = oacc[mt][r];
}

extern "C" void kernel_launch(void* const* d_in, const int* in_sizes, int n_in,
                              void* d_out, int out_size, void* d_ws, size_t ws_size,
                              hipStream_t stream) {
    const float* q = (const float*)d_in[0];
    const float* k = (const float*)d_in[1];
    const float* v = (const float*)d_in[2];
    const void* mask = d_in[3];
    float* attn = (float*)d_out;
    float* outp = attn + (size_t)BB * LL * LL;
    uint32_t* flagp = (uint32_t*)d_ws;

    detect_mask_kernel<<<1, 256, 0, stream>>>((const uint32_t*)mask, flagp);
    fused_attn_kernel<<<dim3((LL / 64) * BB), 256, 0, stream>>>(q, k, v, mask, flagp, attn, outp);
}

// Round 7
// 503.860 us; speedup vs baseline: 1.0027x; 1.0027x over previous
//
#include <hip/hip_runtime.h>
#include <hip/hip_bf16.h>
#include <stdint.h>

#define BB 8
#define LL 4096
#define DD 64
#define KT2 128              // k-columns per iteration
#define NT2 (LL / KT2)       // 32 iterations

typedef short bf16x8 __attribute__((ext_vector_type(8)));
typedef short bf16x4 __attribute__((ext_vector_type(4)));
typedef float f32x4 __attribute__((ext_vector_type(4)));

__device__ inline short f2bfs(float x) {
    __hip_bfloat16 h = __float2bfloat16(x);
    return __builtin_bit_cast(short, h);
}

__device__ inline bf16x8 pack8v(f32x4 a, f32x4 b) {
    bf16x8 r;
    r[0] = f2bfs(a[0]); r[1] = f2bfs(a[1]); r[2] = f2bfs(a[2]); r[3] = f2bfs(a[3]);
    r[4] = f2bfs(b[0]); r[5] = f2bfs(b[1]); r[6] = f2bfs(b[2]); r[7] = f2bfs(b[3]);
    return r;
}

__device__ inline int swzf(int r) { return (r & 7) ^ ((r >> 3) & 7); }

__global__ void detect_mask_kernel(const uint32_t* __restrict__ w, uint32_t* __restrict__ flag) {
    __shared__ int nonbin;
    if (threadIdx.x == 0) nonbin = 0;
    __syncthreads();
    int bad = 0;
    for (int i = threadIdx.x; i < 4096; i += 256) bad |= (w[i] > 1u) ? 1 : 0;
    if (bad) atomicOr(&nonbin, 1);
    __syncthreads();
    if (threadIdx.x == 0) *flag = (uint32_t)(nonbin != 0);
}

// One block = 64 q-rows of one batch, 512 threads = 8 waves (rg = w&3 row-group,
// ch = w>>2 column-half) -> 2 blocks/CU = 16 waves/CU (4/SIMD). Swapped mfma(K,Q)
// keeps 4 consecutive k per lane (vector mask loads / attn stores / Ps writes).
// K, V, and the mask word for tile kt+1 are all prefetched into registers at the
// top of each iteration. Pass 1: exp row sums. Pass 2: recompute QK^T, write
// normalized attn, PV via swizzled Ps/Vt.
__global__ __launch_bounds__(512, 4) void fused_attn_kernel(
    const float* __restrict__ qg, const float* __restrict__ kg,
    const float* __restrict__ vg, const void* __restrict__ maskv,
    const uint32_t* __restrict__ flagp,
    float* __restrict__ attn, float* __restrict__ outp)
{
    __shared__ alignas(16) ushort Kt[2][KT2 * 64];   // bf16 K   [krow][d], swizzled 16B chunks
    __shared__ alignas(16) ushort Vt[2][64 * KT2];   // bf16 V^T [d][k],   swizzled
    __shared__ alignas(16) ushort Ps[64 * KT2];      // bf16 P   [q][k],   swizzled

    const int tid = (int)threadIdx.x;
    const int w   = tid >> 6, l = tid & 63;
    const int lr  = l & 15, lg = l >> 4;
    const int rg  = w & 3, ch = w >> 2;
    const int id  = (int)blockIdx.x;     // id = qt*8 + b
    const int b   = id & 7;
    const int q0  = (id >> 3) * 64;
    const bool mbyte = (*flagp != 0);

    const float* kb = kg + (size_t)b * LL * DD;
    const float* vb = vg + (size_t)b * LL * DD;

    // this lane's q-row; fold the lane's column offset into the row bases
    const int qrow = q0 + 16 * rg + lr;
    const uint8_t* mrow8  = (const uint8_t*)maskv + (size_t)b * LL * LL + (size_t)qrow * LL + ch * 64 + lg * 4;
    const int*     mrow32 = (const int*)maskv     + (size_t)b * LL * LL + (size_t)qrow * LL + ch * 64 + lg * 4;
    float* arow = attn + (size_t)b * LL * LL + (size_t)qrow * LL + ch * 64 + lg * 4;

    // Q fragments, pre-scaled by 1/8 (exact power-of-2)
    bf16x8 qf0, qf1;
    {
        const float* qp = qg + (size_t)(b * LL + qrow) * DD + lg * 8;
        qf0 = pack8v(*(const f32x4*)(qp)      * 0.125f, *(const f32x4*)(qp + 4)  * 0.125f);
        qf1 = pack8v(*(const f32x4*)(qp + 32) * 0.125f, *(const f32x4*)(qp + 36) * 0.125f);
    }

    // ---- K staging: 128x64 f32 -> bf16 (4 float4 loads, 2 b128 commits / thread) ----
    const int krow0 = tid >> 3, kc8 = tid & 7;
    f32x4 ka[4];
    auto kissue = [&](int kbase) {
        #pragma unroll
        for (int m = 0; m < 2; ++m) {
            const float* p = kb + (size_t)(kbase + krow0 + 64 * m) * DD + kc8 * 8;
            ka[2 * m]     = *(const f32x4*)p;
            ka[2 * m + 1] = *(const f32x4*)(p + 4);
        }
    };
    auto kcommit = [&](int buf) {
        #pragma unroll
        for (int m = 0; m < 2; ++m) {
            const int row = krow0 + 64 * m;
            *(bf16x8*)&Kt[buf][row * 64 + ((kc8 ^ swzf(row)) << 3)] = pack8v(ka[2 * m], ka[2 * m + 1]);
        }
    };

    // ---- V staging: 4x4 sub-blocks, register transpose (4 loads, 4 b64 commits) ----
    const int vk4 = tid >> 4, vd4 = tid & 15;
    f32x4 va[4];
    auto vissue = [&](int kbase) {
        #pragma unroll
        for (int it = 0; it < 4; ++it)
            va[it] = *(const f32x4*)(vb + (size_t)(kbase + vk4 * 4 + it) * DD + vd4 * 4);
    };
    auto vcommit = [&](int buf) {
        #pragma unroll
        for (int e = 0; e < 4; ++e) {
            const int d = vd4 * 4 + e;
            bf16x4 t;
            t[0] = f2bfs(va[0][e]); t[1] = f2bfs(va[1][e]);
            t[2] = f2bfs(va[2][e]); t[3] = f2bfs(va[3][e]);
            *(bf16x4*)&Vt[buf][d * KT2 + (((vk4 >> 1) ^ swzf(d)) << 3) + (vk4 & 1) * 4] = t;
        }
    };

    // ================= pass 1: exp row sums =================
    float rsum = 0.f;
    uint32_t mw0 = 0, mw1 = 0, mw2 = 0, mw3 = 0;
    if (mbyte) {
        mw0 = *(const uint32_t*)(mrow8);
        mw1 = *(const uint32_t*)(mrow8 + 16);
        mw2 = *(const uint32_t*)(mrow8 + 32);
        mw3 = *(const uint32_t*)(mrow8 + 48);
    }
    kissue(0); kcommit(0);
    __syncthreads();
    #pragma unroll 1
    for (int kt = 0; kt < NT2; ++kt) {
        const int cur = kt & 1, kbase = kt * KT2;
        const bool more = (kt < NT2 - 1);
        if (more) kissue(kbase + KT2);
        uint32_t nw0 = 0, nw1 = 0, nw2 = 0, nw3 = 0;
        if (mbyte && more) {
            nw0 = *(const uint32_t*)(mrow8 + kbase + KT2);
            nw1 = *(const uint32_t*)(mrow8 + kbase + KT2 + 16);
            nw2 = *(const uint32_t*)(mrow8 + kbase + KT2 + 32);
            nw3 = *(const uint32_t*)(mrow8 + kbase + KT2 + 48);
        }
        #pragma unroll
        for (int n = 0; n < 4; ++n) {
            const int krow = ch * 64 + n * 16 + lr;
            bf16x8 k0 = *(const bf16x8*)&Kt[cur][krow * 64 + ((lg       ^ swzf(krow)) << 3)];
            bf16x8 k1 = *(const bf16x8*)&Kt[cur][krow * 64 + (((4 + lg) ^ swzf(krow)) << 3)];
            f32x4 c = {0.f, 0.f, 0.f, 0.f};
            c = __builtin_amdgcn_mfma_f32_16x16x32_bf16(k0, qf0, c, 0, 0, 0);
            c = __builtin_amdgcn_mfma_f32_16x16x32_bf16(k1, qf1, c, 0, 0, 0);
            if (mbyte) {
                const uint32_t mwc = (n == 0) ? mw0 : (n == 1) ? mw1 : (n == 2) ? mw2 : mw3;
                #pragma unroll
                for (int j = 0; j < 4; ++j)
                    rsum += ((mwc >> (8 * j)) & 0xffu) ? 0.f : __expf(c[j]);
            } else {
                const int4 mi = *(const int4*)(mrow32 + kbase + n * 16);
                rsum += mi.x ? 0.f : __expf(c[0]);
                rsum += mi.y ? 0.f : __expf(c[1]);
                rsum += mi.z ? 0.f : __expf(c[2]);
                rsum += mi.w ? 0.f : __expf(c[3]);
            }
        }
        if (mbyte && more) { mw0 = nw0; mw1 = nw1; mw2 = nw2; mw3 = nw3; }
        if (more) kcommit((kt + 1) & 1);
        __syncthreads();
    }

    // row sum: lg-groups within wave, then the two column-half waves via LDS
    rsum += __shfl_xor(rsum, 16, 64);
    rsum += __shfl_xor(rsum, 32, 64);
    float* Rs = (float*)Ps;                       // Ps unused during pass 1
    if (lg == 0) Rs[ch * 64 + 16 * rg + lr] = rsum;
    __syncthreads();
    const float rinv = 1.0f / (Rs[16 * rg + lr] + Rs[64 + 16 * rg + lr]);

    // ================= pass 2: attn write + PV =================
    f32x4 oacc0 = {0.f, 0.f, 0.f, 0.f}, oacc1 = {0.f, 0.f, 0.f, 0.f};
    if (mbyte) {
        mw0 = *(const uint32_t*)(mrow8);
        mw1 = *(const uint32_t*)(mrow8 + 16);
        mw2 = *(const uint32_t*)(mrow8 + 32);
        mw3 = *(const uint32_t*)(mrow8 + 48);
    }
    kissue(0); vissue(0);
    kcommit(0); vcommit(0);
    __syncthreads();
    #pragma unroll 1
    for (int kt = 0; kt < NT2; ++kt) {
        const int cur = kt & 1, kbase = kt * KT2;
        const bool more = (kt < NT2 - 1);
        if (more) { kissue(kbase + KT2); vissue(kbase + KT2); }
        uint32_t nw0 = 0, nw1 = 0, nw2 = 0, nw3 = 0;
        if (mbyte && more) {
            nw0 = *(const uint32_t*)(mrow8 + kbase + KT2);
            nw1 = *(const uint32_t*)(mrow8 + kbase + KT2 + 16);
            nw2 = *(const uint32_t*)(mrow8 + kbase + KT2 + 32);
            nw3 = *(const uint32_t*)(mrow8 + kbase + KT2 + 48);
        }
        const int prow = 16 * rg + lr;
        #pragma unroll
        for (int n = 0; n < 4; ++n) {
            const int krow = ch * 64 + n * 16 + lr;
            bf16x8 k0 = *(const bf16x8*)&Kt[cur][krow * 64 + ((lg       ^ swzf(krow)) << 3)];
            bf16x8 k1 = *(const bf16x8*)&Kt[cur][krow * 64 + (((4 + lg) ^ swzf(krow)) << 3)];
            f32x4 c = {0.f, 0.f, 0.f, 0.f};
            c = __builtin_amdgcn_mfma_f32_16x16x32_bf16(k0, qf0, c, 0, 0, 0);
            c = __builtin_amdgcn_mfma_f32_16x16x32_bf16(k1, qf1, c, 0, 0, 0);
            f32x4 pv;
            if (mbyte) {
                const uint32_t mwc = (n == 0) ? mw0 : (n == 1) ? mw1 : (n == 2) ? mw2 : mw3;
                #pragma unroll
                for (int j = 0; j < 4; ++j)
                    pv[j] = ((mwc >> (8 * j)) & 0xffu) ? 0.f : __expf(c[j]) * rinv;
            } else {
                const int4 mi = *(const int4*)(mrow32 + kbase + n * 16);
                pv[0] = mi.x ? 0.f : __expf(c[0]) * rinv;
                pv[1] = mi.y ? 0.f : __expf(c[1]) * rinv;
                pv[2] = mi.z ? 0.f : __expf(c[2]) * rinv;
                pv[3] = mi.w ? 0.f : __expf(c[3]) * rinv;
            }
            *(f32x4*)(arow + kbase + n * 16) = pv;
            bf16x4 pb;
            pb[0] = f2bfs(pv[0]); pb[1] = f2bfs(pv[1]);
            pb[2] = f2bfs(pv[2]); pb[3] = f2bfs(pv[3]);
            const int chunk = ch * 8 + n * 2 + (lg >> 1);
            *(bf16x4*)&Ps[prow * KT2 + ((chunk ^ swzf(prow)) << 3) + (lg & 1) * 4] = pb;
        }
        if (mbyte && more) { mw0 = nw0; mw1 = nw1; mw2 = nw2; mw3 = nw3; }
        __syncthreads();   // A: Ps complete; Vt[cur] staged last iteration

        {
            bf16x8 pa[4];
            #pragma unroll
            for (int ks = 0; ks < 4; ++ks)
                pa[ks] = *(const bf16x8*)&Ps[prow * KT2 + ((((ks << 2) + lg) ^ swzf(prow)) << 3)];
            const int d0 = ch * 32 + lr;
            #pragma unroll
            for (int ks = 0; ks < 4; ++ks) {
                bf16x8 vf = *(const bf16x8*)&Vt[cur][d0 * KT2 + ((((ks << 2) + lg) ^ swzf(d0)) << 3)];
                oacc0 = __builtin_amdgcn_mfma_f32_16x16x32_bf16(pa[ks], vf, oacc0, 0, 0, 0);
            }
            const int d1 = d0 + 16;
            #pragma unroll
            for (int ks = 0; ks < 4; ++ks) {
                bf16x8 vf = *(const bf16x8*)&Vt[cur][d1 * KT2 + ((((ks << 2) + lg) ^ swzf(d1)) << 3)];
                oacc1 = __builtin_amdgcn_mfma_f32_16x16x32_bf16(pa[ks], vf, oacc1, 0, 0, 0);
            }
        }

        if (more) { kcommit((kt + 1) & 1); vcommit((kt + 1) & 1); }
        __syncthreads();   // B: commits visible; Ps free for next iteration
    }

    #pragma unroll
    for (int r = 0; r < 4; ++r) {
        const size_t orow = (size_t)(b * LL + q0 + 16 * rg + lg * 4 + r) * DD;
        outp[orow + ch * 32 + lr]      = oacc0[r];
        outp[orow + ch * 32 + 16 + lr] = oacc1[r];
    }
}

extern "C" void kernel_launch(void* const* d_in, const int* in_sizes, int n_in,
                              void* d_out, int out_size, void* d_ws, size_t ws_size,
                              hipStream_t stream) {
    const float* q = (const float*)d_in[0];
    const float* k = (const float*)d_in[1];
    const float* v = (const float*)d_in[2];
    const void* mask = d_in[3];
    float* attn = (float*)d_out;
    float* outp = attn + (size_t)BB * LL * LL;
    uint32_t* flagp = (uint32_t*)d_ws;

    detect_mask_kernel<<<1, 256, 0, stream>>>((const uint32_t*)mask, flagp);
    fused_attn_kernel<<<dim3((LL / 64) * BB), 512, 0, stream>>>(q, k, v, mask, flagp, attn, outp);
}

// Round 8
// 385.815 us; speedup vs baseline: 1.3095x; 1.3060x over previous
//
#include <hip/hip_runtime.h>
#include <hip/hip_bf16.h>
#include <stdint.h>

#define BB 8
#define LL 4096
#define DD 64
#define KT 64                // k-columns per iteration
#define NT (LL / KT)         // 64 iterations

typedef short bf16x8 __attribute__((ext_vector_type(8)));
typedef short bf16x4 __attribute__((ext_vector_type(4)));
typedef short bf16x2 __attribute__((ext_vector_type(2)));
typedef float f32x4 __attribute__((ext_vector_type(4)));

__device__ inline short f2bfs(float x) {
    __hip_bfloat16 h = __float2bfloat16(x);
    return __builtin_bit_cast(short, h);
}

__device__ inline bf16x8 pack8v(f32x4 a, f32x4 b) {
    bf16x8 r;
    r[0] = f2bfs(a[0]); r[1] = f2bfs(a[1]); r[2] = f2bfs(a[2]); r[3] = f2bfs(a[3]);
    r[4] = f2bfs(b[0]); r[5] = f2bfs(b[1]); r[6] = f2bfs(b[2]); r[7] = f2bfs(b[3]);
    return r;
}

__device__ inline int swzf(int r) { return (r & 7) ^ ((r >> 3) & 7); }

__global__ void detect_mask_kernel(const uint32_t* __restrict__ w, uint32_t* __restrict__ flag) {
    __shared__ int nonbin;
    if (threadIdx.x == 0) nonbin = 0;
    __syncthreads();
    int bad = 0;
    for (int i = threadIdx.x; i < 4096; i += 256) bad |= (w[i] > 1u) ? 1 : 0;
    if (bad) atomicOr(&nonbin, 1);
    __syncthreads();
    if (threadIdx.x == 0) *flag = (uint32_t)(nonbin != 0);
}

// One block = 64 q-rows of one batch, 512 threads = 8 waves (rg=w&3 row-group,
// ch=w>>2 column-half) -> 2 blocks/CU. Swapped mfma(K,Q): 4 consecutive k per
// lane (vector mask loads / attn stores / Ps writes). Mask is read from HBM
// ONCE (pass 1); per-lane bits cached in LDS (Msk, 32 KB) for pass 2 -- the
// round-6/7 mask re-read regression showed this cache is worth ~120 us.
__global__ __launch_bounds__(512, 4) void fused_attn_kernel(
    const float* __restrict__ qg, const float* __restrict__ kg,
    const float* __restrict__ vg, const void* __restrict__ maskv,
    const uint32_t* __restrict__ flagp,
    float* __restrict__ attn, float* __restrict__ outp)
{
    __shared__ alignas(16) ushort Kt[2][KT * 64];   // bf16 K   [krow][d], swizzled (16 KB)
    __shared__ alignas(16) ushort Vt[2][64 * KT];   // bf16 V^T [d][k],   swizzled (16 KB)
    __shared__ alignas(16) ushort Ps[64 * KT];      // bf16 P   [q][k],   swizzled (8 KB)
    __shared__ uint8_t Msk[8][NT][64];              // mask bits [wave][tile][lane] (32 KB)

    const int tid = (int)threadIdx.x;
    const int w   = tid >> 6, l = tid & 63;
    const int lr  = l & 15, lg = l >> 4;
    const int rg  = w & 3, ch = w >> 2;
    const int id  = (int)blockIdx.x;     // id = qt*8 + b
    const int b   = id & 7;
    const int q0  = (id >> 3) * 64;
    const bool mbyte = (*flagp != 0);

    const float* kb = kg + (size_t)b * LL * DD;
    const float* vb = vg + (size_t)b * LL * DD;

    // this lane's q-row; fold the lane's column offset into the row bases
    const int qrow = q0 + 16 * rg + lr;
    const uint8_t* mrow8  = (const uint8_t*)maskv + (size_t)b * LL * LL + (size_t)qrow * LL + ch * 32 + lg * 4;
    const int*     mrow32 = (const int*)maskv     + (size_t)b * LL * LL + (size_t)qrow * LL + ch * 32 + lg * 4;
    float* arow = attn + (size_t)b * LL * LL + (size_t)qrow * LL + ch * 32 + lg * 4;

    // Q fragments, pre-scaled by 1/8 (exact power-of-2)
    bf16x8 qf0, qf1;
    {
        const float* qp = qg + (size_t)(b * LL + qrow) * DD + lg * 8;
        qf0 = pack8v(*(const f32x4*)(qp)      * 0.125f, *(const f32x4*)(qp + 4)  * 0.125f);
        qf1 = pack8v(*(const f32x4*)(qp + 32) * 0.125f, *(const f32x4*)(qp + 36) * 0.125f);
    }

    // ---- K staging: 64x64 f32 -> bf16 (2 float4 loads, 1 b128 commit / thread) ----
    const int krow0 = tid >> 3, kc8 = tid & 7;
    f32x4 ka0, ka1;
    auto kissue = [&](int kbase) {
        const float* p = kb + (size_t)(kbase + krow0) * DD + kc8 * 8;
        ka0 = *(const f32x4*)p;
        ka1 = *(const f32x4*)(p + 4);
    };
    auto kcommit = [&](int buf) {
        *(bf16x8*)&Kt[buf][krow0 * 64 + ((kc8 ^ swzf(krow0)) << 3)] = pack8v(ka0, ka1);
    };

    // ---- V staging: 2 k-rows x 4 d / thread, register transpose, b32 commits ----
    const int vk2 = tid >> 4, vd4 = tid & 15;
    f32x4 va0, va1;
    auto vissue = [&](int kbase) {
        const float* p = vb + (size_t)(kbase + vk2 * 2) * DD + vd4 * 4;
        va0 = *(const f32x4*)p;
        va1 = *(const f32x4*)(p + DD);
    };
    auto vcommit = [&](int buf) {
        const int k0 = vk2 * 2;
        #pragma unroll
        for (int e = 0; e < 4; ++e) {
            const int d = vd4 * 4 + e;
            bf16x2 t;
            t[0] = f2bfs(va0[e]);
            t[1] = f2bfs(va1[e]);
            *(bf16x2*)&Vt[buf][d * 64 + ((((k0 >> 3) ^ swzf(d))) << 3) + (k0 & 7)] = t;
        }
    };

    // ================= pass 1: exp row sums + mask bit cache =================
    float rsum = 0.f;
    uint32_t mw0 = 0, mw1 = 0;
    if (mbyte) {
        mw0 = *(const uint32_t*)(mrow8);
        mw1 = *(const uint32_t*)(mrow8 + 16);
    }
    kissue(0); kcommit(0);
    __syncthreads();
    #pragma unroll 1
    for (int kt = 0; kt < NT; ++kt) {
        const int cur = kt & 1, kbase = kt * KT;
        const bool more = (kt < NT - 1);
        if (more) kissue(kbase + KT);
        uint32_t nw0 = 0, nw1 = 0;
        if (mbyte && more) {
            nw0 = *(const uint32_t*)(mrow8 + kbase + KT);
            nw1 = *(const uint32_t*)(mrow8 + kbase + KT + 16);
        }
        uint32_t mbits = 0;
        #pragma unroll
        for (int n = 0; n < 2; ++n) {
            const int krow = ch * 32 + n * 16 + lr;
            bf16x8 k0 = *(const bf16x8*)&Kt[cur][krow * 64 + ((lg       ^ swzf(krow)) << 3)];
            bf16x8 k1 = *(const bf16x8*)&Kt[cur][krow * 64 + (((4 + lg) ^ swzf(krow)) << 3)];
            f32x4 c = {0.f, 0.f, 0.f, 0.f};
            c = __builtin_amdgcn_mfma_f32_16x16x32_bf16(k0, qf0, c, 0, 0, 0);
            c = __builtin_amdgcn_mfma_f32_16x16x32_bf16(k1, qf1, c, 0, 0, 0);
            if (mbyte) {
                const uint32_t mwc = n ? mw1 : mw0;
                #pragma unroll
                for (int j = 0; j < 4; ++j) {
                    const uint32_t mk = (mwc >> (8 * j)) & 0xffu;
                    mbits |= (mk ? 1u : 0u) << (n * 4 + j);
                    rsum += mk ? 0.f : __expf(c[j]);
                }
            } else {
                const int4 mi = *(const int4*)(mrow32 + kbase + n * 16);
                const int mk[4] = {mi.x, mi.y, mi.z, mi.w};
                #pragma unroll
                for (int j = 0; j < 4; ++j) {
                    mbits |= (mk[j] ? 1u : 0u) << (n * 4 + j);
                    rsum += mk[j] ? 0.f : __expf(c[j]);
                }
            }
        }
        Msk[w][kt][l] = (uint8_t)mbits;
        mw0 = nw0; mw1 = nw1;
        if (more) kcommit((kt + 1) & 1);
        __syncthreads();
    }

    // row sum: lg-groups within wave, then the two column-half waves via LDS
    rsum += __shfl_xor(rsum, 16, 64);
    rsum += __shfl_xor(rsum, 32, 64);
    float* Rs = (float*)Ps;                       // Ps unused during pass 1
    if (lg == 0) Rs[ch * 64 + 16 * rg + lr] = rsum;
    __syncthreads();
    const float rinv = 1.0f / (Rs[16 * rg + lr] + Rs[64 + 16 * rg + lr]);

    // ================= pass 2: attn write + PV =================
    f32x4 oacc0 = {0.f, 0.f, 0.f, 0.f}, oacc1 = {0.f, 0.f, 0.f, 0.f};
    kissue(0); vissue(0);
    kcommit(0); vcommit(0);
    __syncthreads();
    #pragma unroll 1
    for (int kt = 0; kt < NT; ++kt) {
        const int cur = kt & 1, kbase = kt * KT;
        const bool more = (kt < NT - 1);
        if (more) { kissue(kbase + KT); vissue(kbase + KT); }
        const int mb = (int)Msk[w][kt][l];
        const int prow = 16 * rg + lr;
        #pragma unroll
        for (int n = 0; n < 2; ++n) {
            const int krow = ch * 32 + n * 16 + lr;
            bf16x8 k0 = *(const bf16x8*)&Kt[cur][krow * 64 + ((lg       ^ swzf(krow)) << 3)];
            bf16x8 k1 = *(const bf16x8*)&Kt[cur][krow * 64 + (((4 + lg) ^ swzf(krow)) << 3)];
            f32x4 c = {0.f, 0.f, 0.f, 0.f};
            c = __builtin_amdgcn_mfma_f32_16x16x32_bf16(k0, qf0, c, 0, 0, 0);
            c = __builtin_amdgcn_mfma_f32_16x16x32_bf16(k1, qf1, c, 0, 0, 0);
            f32x4 pv;
            #pragma unroll
            for (int j = 0; j < 4; ++j)
                pv[j] = ((mb >> (n * 4 + j)) & 1) ? 0.f : __expf(c[j]) * rinv;
            *(f32x4*)(arow + kbase + n * 16) = pv;
            bf16x4 pb;
            pb[0] = f2bfs(pv[0]); pb[1] = f2bfs(pv[1]);
            pb[2] = f2bfs(pv[2]); pb[3] = f2bfs(pv[3]);
            const int chunk = ch * 4 + n * 2 + (lg >> 1);
            *(bf16x4*)&Ps[prow * 64 + ((chunk ^ swzf(prow)) << 3) + (lg & 1) * 4] = pb;
        }
        __syncthreads();   // A: Ps complete; Vt[cur] staged last iteration

        {
            bf16x8 pa[2];
            #pragma unroll
            for (int ks = 0; ks < 2; ++ks)
                pa[ks] = *(const bf16x8*)&Ps[prow * 64 + ((((ks << 2) + lg) ^ swzf(prow)) << 3)];
            const int d0 = ch * 32 + lr;
            const int d1 = d0 + 16;
            #pragma unroll
            for (int ks = 0; ks < 2; ++ks) {
                bf16x8 vf = *(const bf16x8*)&Vt[cur][d0 * 64 + ((((ks << 2) + lg) ^ swzf(d0)) << 3)];
                oacc0 = __builtin_amdgcn_mfma_f32_16x16x32_bf16(pa[ks], vf, oacc0, 0, 0, 0);
            }
            #pragma unroll
            for (int ks = 0; ks < 2; ++ks) {
                bf16x8 vf = *(const bf16x8*)&Vt[cur][d1 * 64 + ((((ks << 2) + lg) ^ swzf(d1)) << 3)];
                oacc1 = __builtin_amdgcn_mfma_f32_16x16x32_bf16(pa[ks], vf, oacc1, 0, 0, 0);
            }
        }

        if (more) { kcommit((kt + 1) & 1); vcommit((kt + 1) & 1); }
        __syncthreads();   // B: commits visible; Ps free for next iteration
    }

    #pragma unroll
    for (int r = 0; r < 4; ++r) {
        const size_t orow = (size_t)(b * LL + q0 + 16 * rg + lg * 4 + r) * DD;
        outp[orow + ch * 32 + lr]      = oacc0[r];
        outp[orow + ch * 32 + 16 + lr] = oacc1[r];
    }
}

extern "C" void kernel_launch(void* const* d_in, const int* in_sizes, int n_in,
                              void* d_out, int out_size, void* d_ws, size_t ws_size,
                              hipStream_t stream) {
    const float* q = (const float*)d_in[0];
    const float* k = (const float*)d_in[1];
    const float* v = (const float*)d_in[2];
    const void* mask = d_in[3];
    float* attn = (float*)d_out;
    float* outp = attn + (size_t)BB * LL * LL;
    uint32_t* flagp = (uint32_t*)d_ws;

    detect_mask_kernel<<<1, 256, 0, stream>>>((const uint32_t*)mask, flagp);
    fused_attn_kernel<<<dim3((LL / 64) * BB), 512, 0, stream>>>(q, k, v, mask, flagp, attn, outp);
}